// Round 1
// baseline (244.228 us; speedup 1.0000x reference)
//
#include <hip/hip_runtime.h>
#include <math.h>

// EqualtimeLayer R14: replace the chunked block-scan solver (run_epoch) with
// bucket-aggregate prefix scans + fully thread-local candidate evaluation.
//
// Per (b,post): t = spike[b][pre] + delay[pre][post]. Crossing candidate at
// sorted position k: tmp = (theta + cumWT_k)/cumW_k, valid iff cumW>0,
// tmp >= t_k, tmp <= t_{k+1}. Valid candidates are monotone in k, so the
// earliest valid candidate == min over ALL valid candidates -> no sequential
// chunk loop / early exit needed.
//
// New scheme (vs R13's run_epoch):
//  - hist phase accumulates per-bucket {cnt (int), W=sum w, WT=sum w*t (f32
//    LDS atomics -> ds_add_f32), minT (int-bits atomicMin)}.
//  - one wave-redundant scan phase (256 buckets = 1 int4/lane): exclusive
//    prefix of cnt (scatter bases), W, WT, and a suffix-min of minT
//    (next-event lookup), written back IN PLACE by wave 0.
//  - scatter (t,w) by bucket as before; the fixup mates-loop now also yields
//    intra-bucket prefix sums and next-mate time, so each thread finishes its
//    own events' candidates without any block-wide scan or reorder.
//  - 5 barriers/batch (was ~8-9); s_agg double-buffered so re-zeroing folds
//    into the candidate phase (next stage's buffer is always clean at entry).
//  - fallback (no valid low candidate, ~1-2%): identical stage over the tail
//    [0.625,2.0) with base sums = low-stage scan totals. Exact.

#define B_TOT 32
#define PRE 1024
#define POST 1024
#define NB 256
#define TPB 256
#define EPT 4
#define BPW 8
#define TCUTF 0.625f
#define BSCALE 409.6f          // 256 buckets over [0, 0.625)
#define BSCALE2 186.18181818f  // 256 buckets over [0.625, 2.0)
#define INFB 0x7F800000

// ---- DPP helpers (gfx9 encodings) ----
template<int CTRL, int MASK>
__device__ __forceinline__ int dpp_add_i32(int v) {
    return v + __builtin_amdgcn_update_dpp(0, v, CTRL, MASK, 0xf, true);
}
template<int CTRL, int MASK>
__device__ __forceinline__ float dpp_add_f32(float v) {
    int t = __builtin_amdgcn_update_dpp(0, __float_as_int(v), CTRL, MASK, 0xf, true);
    return v + __int_as_float(t);
}
template<int CTRL, int MASK>
__device__ __forceinline__ int dpp_min_i32(int v) {
    // old = +INF bits, bound_ctrl=false: invalid/row-masked lanes see INF (min identity)
    int t = __builtin_amdgcn_update_dpp(INFB, v, CTRL, MASK, 0xf, false);
    return min(v, t);
}
template<int CTRL>
__device__ __forceinline__ float dpp_min_f32(float v) {
    int t = __builtin_amdgcn_update_dpp(__float_as_int(v), __float_as_int(v), CTRL, 0xf, 0xf, false);
    return fminf(v, __int_as_float(t));
}
__device__ __forceinline__ int wave_iscan_i32(int v) {
    v = dpp_add_i32<0x111, 0xf>(v);
    v = dpp_add_i32<0x112, 0xf>(v);
    v = dpp_add_i32<0x114, 0xf>(v);
    v = dpp_add_i32<0x118, 0xf>(v);
    v = dpp_add_i32<0x142, 0xa>(v);
    v = dpp_add_i32<0x143, 0xc>(v);
    return v;
}
__device__ __forceinline__ float wave_iscan_f32(float v) {
    v = dpp_add_f32<0x111, 0xf>(v);
    v = dpp_add_f32<0x112, 0xf>(v);
    v = dpp_add_f32<0x114, 0xf>(v);
    v = dpp_add_f32<0x118, 0xf>(v);
    v = dpp_add_f32<0x142, 0xa>(v);
    v = dpp_add_f32<0x143, 0xc>(v);
    return v;
}
__device__ __forceinline__ int wave_iscan_min_i32(int v) {
    v = dpp_min_i32<0x111, 0xf>(v);
    v = dpp_min_i32<0x112, 0xf>(v);
    v = dpp_min_i32<0x114, 0xf>(v);
    v = dpp_min_i32<0x118, 0xf>(v);
    v = dpp_min_i32<0x142, 0xa>(v);
    v = dpp_min_i32<0x143, 0xc>(v);
    return v;
}
__device__ __forceinline__ float wave_min_f32(float v) {
    v = fminf(v, __shfl_down(v, 32));
    v = fminf(v, __shfl_down(v, 16));
    v = dpp_min_f32<0x140>(v);
    v = dpp_min_f32<0x141>(v);
    v = dpp_min_f32<0x4E>(v);
    v = dpp_min_f32<0xB1>(v);
    return v;
}
__device__ __forceinline__ int clampb(int k) {
    return k < 0 ? 0 : (k > NB - 1 ? NB - 1 : k);
}

// One stage over the events marked bkt[j] >= 0.
// agg  : this stage's aggregate buffer, 4*NB ints, MUST be pre-zeroed
//        (cnt=0, W=0, WT=0, minT=INF). Layout [cnt | W | WT | minT];
//        overwritten in place by the scan to [pck | CW | CWT | SUF].
// aggZ : the other buffer; re-initialized here for the NEXT stage.
// IS_LOW: collect min of excluded events (stage end), via s_red.
// Returns block-wide min valid candidate (INF if none).
template<bool IS_LOW>
__device__ __forceinline__ float do_stage(
    int* agg, int* aggZ,
    float* s_t, float* s_w, float* s_red,
    const float (&tv)[EPT], const float (&wgt)[EPT],
    int (&bkt)[EPT], int (&rnk)[EPT],
    float theta, float Wbase, float WTbase,
    float& totW, float& totWT, int& Ntot,
    int tid, int lane, int wid)
{
    // ---- hist: cnt / W / WT / minT per bucket ----
    float mloc = INFINITY;
#pragma unroll
    for (int j = 0; j < EPT; ++j) {
        int k = bkt[j];
        if (k >= 0) {
            float t = tv[j], w = wgt[j];
            rnk[j] = atomicAdd(&agg[k], 1);
            atomicAdd(reinterpret_cast<float*>(agg) + NB + k, w);       // ds_add_f32
            atomicAdd(reinterpret_cast<float*>(agg) + 2 * NB + k, w * t);
            atomicMin(&agg[3 * NB + k], __float_as_int(t));             // t>=0: bit order ok
        } else if (IS_LOW) {
            mloc = fminf(mloc, tv[j]);
        }
    }
    __syncthreads();                                       // B1: atomics final

    if (IS_LOW) {
        mloc = wave_min_f32(mloc);
        if (lane == 0) s_red[wid] = mloc;                  // read back post-B3
    }

    // ---- load aggregates (all waves, redundant) ----
    int4 c4 = reinterpret_cast<const int4*>(agg)[lane];
    int4 w4 = reinterpret_cast<const int4*>(agg + NB)[lane];
    int4 q4 = reinterpret_cast<const int4*>(agg + 2 * NB)[lane];
    int4 m4 = reinterpret_cast<const int4*>(agg + 3 * NB)[lane];
    __syncthreads();                                       // B2: all reads done

    // ---- scans (wave-redundant; wave 0 writes back in place) ----
    // counts -> packed (off<<12 | cnt)
    int cl[4] = {c4.x, c4.y, c4.z, c4.w};
    int le[4]; int ls = 0;
#pragma unroll
    for (int j = 0; j < 4; ++j) { le[j] = ls; ls += cl[j]; }
    int xi = wave_iscan_i32(ls);
    int ei = xi - ls;
    Ntot = __builtin_amdgcn_readlane(xi, 63);

    // W -> exclusive prefix CW
    float wl[4] = {__int_as_float(w4.x), __int_as_float(w4.y),
                   __int_as_float(w4.z), __int_as_float(w4.w)};
    float lew[4]; float lsw = 0.f;
#pragma unroll
    for (int j = 0; j < 4; ++j) { lew[j] = lsw; lsw += wl[j]; }
    float xw = wave_iscan_f32(lsw);
    float ew = xw - lsw;
    totW = __int_as_float(__builtin_amdgcn_readlane(__float_as_int(xw), 63));

    // WT -> exclusive prefix CWT
    float ql[4] = {__int_as_float(q4.x), __int_as_float(q4.y),
                   __int_as_float(q4.z), __int_as_float(q4.w)};
    float leq[4]; float lsq = 0.f;
#pragma unroll
    for (int j = 0; j < 4; ++j) { leq[j] = lsq; lsq += ql[j]; }
    float xq = wave_iscan_f32(lsq);
    float eq = xq - lsq;
    totWT = __int_as_float(__builtin_amdgcn_readlane(__float_as_int(xq), 63));

    // minT -> suffix-min over strictly-later buckets (int bits)
    int mi[4] = {m4.x, m4.y, m4.z, m4.w};
    int gm = min(min(mi[0], mi[1]), min(mi[2], mi[3]));
    int rg = __shfl(gm, 63 - lane);                        // reversed group array
    int im = wave_iscan_min_i32(rg);                       // inclusive fwd min
    int pm = __shfl_up(im, 1);
    int er = (lane == 0) ? INFB : pm;                      // exclusive fwd min
    int sg = __shfl(er, 63 - lane);                        // min over groups > lane
    int sf[4];
    sf[3] = sg;
    sf[2] = min(mi[3], sf[3]);
    sf[1] = min(mi[2], sf[2]);
    sf[0] = min(mi[1], sf[1]);

    if (wid == 0) {
        int4 o0, o1, o2, o3;
        o0.x = ((ei + le[0]) << 12) | cl[0];
        o0.y = ((ei + le[1]) << 12) | cl[1];
        o0.z = ((ei + le[2]) << 12) | cl[2];
        o0.w = ((ei + le[3]) << 12) | cl[3];
        o1 = make_int4(__float_as_int(ew + lew[0]), __float_as_int(ew + lew[1]),
                       __float_as_int(ew + lew[2]), __float_as_int(ew + lew[3]));
        o2 = make_int4(__float_as_int(eq + leq[0]), __float_as_int(eq + leq[1]),
                       __float_as_int(eq + leq[2]), __float_as_int(eq + leq[3]));
        o3 = make_int4(sf[0], sf[1], sf[2], sf[3]);
        reinterpret_cast<int4*>(agg)[lane] = o0;
        reinterpret_cast<int4*>(agg + NB)[lane] = o1;
        reinterpret_cast<int4*>(agg + 2 * NB)[lane] = o2;
        reinterpret_cast<int4*>(agg + 3 * NB)[lane] = o3;
    }
    __syncthreads();                                       // B3: packed visible

    float stageEnd = INFINITY;
    if (IS_LOW)
        stageEnd = fminf(fminf(s_red[0], s_red[1]), fminf(s_red[2], s_red[3]));

    // ---- scatter (arrival order within bucket) ----
    int pk[EPT];
#pragma unroll
    for (int j = 0; j < EPT; ++j) {
        if (bkt[j] >= 0) {
            pk[j] = agg[bkt[j]];
            int pos = (pk[j] >> 12) + rnk[j];
            s_t[pos] = tv[j];
            s_w[pos] = wgt[j];
            rnk[j] = pos;                                  // absolute position
        }
    }
    __syncthreads();                                       // B4: scatter visible

    // ---- thread-local candidates + re-init other buffer ----
    float mc = INFINITY;
#pragma unroll
    for (int j = 0; j < EPT; ++j) {
        if (bkt[j] < 0) continue;
        int k = bkt[j];
        int bas = pk[j] >> 12, cn = pk[j] & 0xfff;
        int p0 = rnk[j];
        float t_e = tv[j], w_e = wgt[j];
        float CW  = __int_as_float(agg[NB + k]);
        float CWT = __int_as_float(agg[2 * NB + k]);
        float tnx = fminf(__int_as_float(agg[3 * NB + k]), stageEnd);
        float iw = 0.f, iwt = 0.f;
        if (cn > 1) {
            for (int q = bas; q < bas + cn; ++q) {
                if (q == p0) continue;
                float tq = s_t[q], wq = s_w[q];
                bool earlier = (tq < t_e) || (tq == t_e && q < p0);
                if (earlier) { iw += wq; iwt += wq * tq; }
                else         tnx = fminf(tnx, tq);
            }
        }
        float cw = Wbase + CW + iw + w_e;
        if (cw > 0.f) {
            float tmp = (theta + WTbase + CWT + iwt + w_e * t_e) * __builtin_amdgcn_rcpf(cw);
            if (tmp >= t_e && tmp <= tnx) mc = fminf(mc, tmp);
        }
    }
    {   // next stage's buffer: cnt/W/WT = 0, minT = +INF
        int4 z = (tid >> 6) == 3 ? make_int4(INFB, INFB, INFB, INFB)
                                 : make_int4(0, 0, 0, 0);
        reinterpret_cast<int4*>(aggZ)[tid] = z;
    }
    mc = wave_min_f32(mc);
    if (lane == 0) s_red[wid] = mc;
    __syncthreads();                                       // B5: mins + zero visible
    return fminf(fminf(s_red[0], s_red[1]), fminf(s_red[2], s_red[3]));
}

__global__ __launch_bounds__(TPB, 8) void equaltime_kernel(
    const float* __restrict__ spikes,     // [B][PRE]
    const float* __restrict__ weights,    // [PRE][POST]
    const float* __restrict__ delays,     // [PRE][POST]
    const float* __restrict__ thresholds, // [POST]
    float* __restrict__ out)              // [B][POST]
{
    __shared__ __align__(16) float s_t[PRE];       // 4 KB
    __shared__ __align__(16) float s_w[PRE];       // 4 KB
    __shared__ __align__(16) int   s_agg[2][4 * NB]; // 2 x 4 KB, double-buffered
    __shared__ float s_red[4];

    const int tid  = threadIdx.x;
    const int lane = tid & 63;
    const int wid  = tid >> 6;

    // XCD-contiguous swizzle for weight/delay L2 locality
    const int bx   = blockIdx.x;
    const int sbx  = (bx & 7) * 512 + (bx >> 3);
    const int post = sbx >> 2;            // 4 WGs per post
    const int b0   = (sbx & 3) * BPW;
    const float theta = thresholds[post];

    float dly[EPT], wgt[EPT];
#pragma unroll
    for (int j = 0; j < EPT; ++j) {
        int pre = tid * EPT + j;
        dly[j] = delays[pre * POST + post];
        wgt[j] = weights[pre * POST + post];
    }

    // init both aggregate buffers
    {
        int4 z = (tid >> 6) == 3 ? make_int4(INFB, INFB, INFB, INFB)
                                 : make_int4(0, 0, 0, 0);
        reinterpret_cast<int4*>(s_agg[0])[tid] = z;
        reinterpret_cast<int4*>(s_agg[1])[tid] = z;
    }
    __syncthreads();

    int pb = 0;
    for (int bi = 0; bi < BPW; ++bi) {
        const int b = b0 + bi;
        float4 sp = *reinterpret_cast<const float4*>(spikes + b * PRE + tid * EPT);
        float tv[EPT] = {sp.x + dly[0], sp.y + dly[1], sp.z + dly[2], sp.w + dly[3]};
        int bkt[EPT], rnk[EPT];
#pragma unroll
        for (int j = 0; j < EPT; ++j) {
            int k = (int)(tv[j] * BSCALE);
            bkt[j] = (k < NB) ? k : -1;            // -1 => excluded (tail)
        }

        float totW, totWT; int Nlow;
        float mAll = do_stage<true>(s_agg[pb], s_agg[pb ^ 1], s_t, s_w, s_red,
                                    tv, wgt, bkt, rnk, theta, 0.f, 0.f,
                                    totW, totWT, Nlow, tid, lane, wid);
        pb ^= 1;

        // rare exact fallback: no valid crossing among t < TCUT
        if (!(mAll < INFINITY) && Nlow < PRE) {
#pragma unroll
            for (int j = 0; j < EPT; ++j) {
                bkt[j] = (bkt[j] < 0) ? clampb((int)((tv[j] - TCUTF) * BSCALE2)) : -1;
            }
            float d1, d2; int d3;
            mAll = do_stage<false>(s_agg[pb], s_agg[pb ^ 1], s_t, s_w, s_red,
                                   tv, wgt, bkt, rnk, theta, totW, totWT,
                                   d1, d2, d3, tid, lane, wid);
            pb ^= 1;
        }

        if (tid == 0) out[b * POST + post] = mAll;
        // No trailing barrier: next stage's hist atomics target the buffer
        // zeroed before B5 of this stage -> barrier-ordered.
    }
}

extern "C" void kernel_launch(void* const* d_in, const int* in_sizes, int n_in,
                              void* d_out, int out_size, void* d_ws, size_t ws_size,
                              hipStream_t stream) {
    const float* spikes     = (const float*)d_in[0]; // [32,1024]
    const float* weights    = (const float*)d_in[1]; // [1024,1024]
    const float* delays     = (const float*)d_in[2]; // [1024,1024]
    const float* thresholds = (const float*)d_in[3]; // [1024]
    float* outp = (float*)d_out;                     // [32,1024]

    dim3 grid(POST * (B_TOT / BPW)); // 4096 workgroups
    dim3 block(TPB);
    equaltime_kernel<<<grid, block, 0, stream>>>(spikes, weights, delays, thresholds, outp);
}

// Round 2
// 168.137 us; speedup vs baseline: 1.4526x; 1.4526x over previous
//
#include <hip/hip_runtime.h>
#include <math.h>

// EqualtimeLayer R15 = R13 skeleton (BPW=8, NB=512, spill-free envelope) with
// the reorder-free solver proven exact in R14 (absmax 0.0 there):
//  - hist: count atomic (rank) + minT atomicMin per event. No W/WT atomics
//    (R14's 4-atomic hist + 3 wave-redundant f32 scans caused the spill+VALU
//    regression: WRITE_SIZE 128KB -> 8.3MB).
//  - wave 0 ONLY: count scan -> s_pck (off<<12|cnt) and bucket suffix-min
//    s_minT -> s_sfx (reversed-DPP-scan trick, R14-verified). Waves 1-3 read
//    N_low from LDS. Saves 3x redundant scan issue.
//  - scatter by bucket (arrival order); NO physical reorder afterwards.
//  - solve: block f32 scans over POSITION order (prefix at bucket boundaries
//    is permutation-invariant); each thread corrects its own position-prefix
//    to time-order via a single mates loop (delta = [time-earlier]w -
//    [position-earlier]w), gets next-event time from later mates + s_sfx.
//    Valid candidates are monotone in k => min over all valid is exact, so
//    the chunk early-exit, rank-gather (np/np2), fixup and per-chunk reduce
//    are all deleted. 5 barriers/batch (was ~9).
//  - fallback (no valid low candidate, rare): identical machinery over the
//    tail [0.625,2.0), carrying cumW/cumWT. Exact.

#define B_TOT 32
#define PRE 1024
#define POST 1024
#define NB 512
#define TPB 256
#define EPT 4
#define BPW 8
#define CHUNK 256
#define TCUTF 0.625f
#define BSCALE 819.2f          // 512 buckets over [0, 0.625)
#define BSCALE2 372.36363636f  // 512 buckets over [0.625, 2.0)
#define INFB 0x7F800000

// ---- DPP helpers (gfx9 encodings) ----
template<int CTRL, int MASK>
__device__ __forceinline__ int dpp_add_i32(int v) {
    return v + __builtin_amdgcn_update_dpp(0, v, CTRL, MASK, 0xf, true);
}
template<int CTRL, int MASK>
__device__ __forceinline__ float dpp_add_f32(float v) {
    int t = __builtin_amdgcn_update_dpp(0, __float_as_int(v), CTRL, MASK, 0xf, true);
    return v + __int_as_float(t);
}
template<int CTRL, int MASK>
__device__ __forceinline__ int dpp_min_i32(int v) {
    // old = +INF bits, bound_ctrl=false: missing lanes contribute min identity
    int t = __builtin_amdgcn_update_dpp(INFB, v, CTRL, MASK, 0xf, false);
    return min(v, t);
}
template<int CTRL>
__device__ __forceinline__ float dpp_min_f32(float v) {
    int t = __builtin_amdgcn_update_dpp(__float_as_int(v), __float_as_int(v), CTRL, 0xf, 0xf, false);
    return fminf(v, __int_as_float(t));
}
__device__ __forceinline__ int wave_iscan_i32(int v) {
    v = dpp_add_i32<0x111, 0xf>(v);
    v = dpp_add_i32<0x112, 0xf>(v);
    v = dpp_add_i32<0x114, 0xf>(v);
    v = dpp_add_i32<0x118, 0xf>(v);
    v = dpp_add_i32<0x142, 0xa>(v);
    v = dpp_add_i32<0x143, 0xc>(v);
    return v;
}
__device__ __forceinline__ float wave_iscan_f32(float v) {
    v = dpp_add_f32<0x111, 0xf>(v);
    v = dpp_add_f32<0x112, 0xf>(v);
    v = dpp_add_f32<0x114, 0xf>(v);
    v = dpp_add_f32<0x118, 0xf>(v);
    v = dpp_add_f32<0x142, 0xa>(v);
    v = dpp_add_f32<0x143, 0xc>(v);
    return v;
}
__device__ __forceinline__ int wave_iscan_min_i32(int v) {
    v = dpp_min_i32<0x111, 0xf>(v);
    v = dpp_min_i32<0x112, 0xf>(v);
    v = dpp_min_i32<0x114, 0xf>(v);
    v = dpp_min_i32<0x118, 0xf>(v);
    v = dpp_min_i32<0x142, 0xa>(v);
    v = dpp_min_i32<0x143, 0xc>(v);
    return v;
}
__device__ __forceinline__ float wave_min_f32(float v) {
    v = fminf(v, __shfl_down(v, 32));
    v = fminf(v, __shfl_down(v, 16));
    v = dpp_min_f32<0x140>(v);
    v = dpp_min_f32<0x141>(v);
    v = dpp_min_f32<0x4E>(v);
    v = dpp_min_f32<0xB1>(v);
    return v;
}
__device__ __forceinline__ int clampb(int k) {
    return k < 0 ? 0 : (k > NB - 1 ? NB - 1 : k);
}

// Wave-0-only: exclusive scan of NB counts (raw -> pck, packed off<<12|cnt),
// suffix-min of bucket minT (mnt -> sfx: min t over buckets STRICTLY later),
// total count -> *nout. Layout: half1 = buckets[4L..4L+3] at int4 [lane],
// half2 = buckets[256+4L..] at [lane+64] (R13-proven conflict-free).
__device__ __forceinline__ void scan_and_suffix(const int* raw, int* pck,
                                                const int* mnt, int* sfx,
                                                int* nout, int lane) {
    int4 a = reinterpret_cast<const int4*>(raw)[lane];
    int4 b = reinterpret_cast<const int4*>(raw)[lane + 64];
    int c1[4] = {a.x, a.y, a.z, a.w};
    int c2[4] = {b.x, b.y, b.z, b.w};
    int ls1[4], ls2[4];
    int s1 = 0, s2 = 0;
#pragma unroll
    for (int j = 0; j < 4; ++j) { s1 += c1[j]; ls1[j] = s1; }
#pragma unroll
    for (int j = 0; j < 4; ++j) { s2 += c2[j]; ls2[j] = s2; }
    int x1 = wave_iscan_i32(s1);
    int x2 = wave_iscan_i32(s2);
    int tot1 = __builtin_amdgcn_readlane(x1, 63);
    int tot2 = __builtin_amdgcn_readlane(x2, 63);
    int e1 = x1 - s1;
    int e2 = tot1 + x2 - s2;
    {
        int o1[4], o2[4];
#pragma unroll
        for (int j = 0; j < 4; ++j) {
            o1[j] = ((e1 + ls1[j] - c1[j]) << 12) | c1[j];
            o2[j] = ((e2 + ls2[j] - c2[j]) << 12) | c2[j];
        }
        reinterpret_cast<int4*>(pck)[lane]      = make_int4(o1[0], o1[1], o1[2], o1[3]);
        reinterpret_cast<int4*>(pck)[lane + 64] = make_int4(o2[0], o2[1], o2[2], o2[3]);
    }
    if (lane == 0) *nout = tot1 + tot2;

    // ---- suffix-min (reversed iscan-min; R14-verified pattern) ----
    int4 ma = reinterpret_cast<const int4*>(mnt)[lane];
    int4 mb = reinterpret_cast<const int4*>(mnt)[lane + 64];
    // half 2 first (its total feeds half 1)
    int m2[4] = {mb.x, mb.y, mb.z, mb.w};
    int g2 = min(min(m2[0], m2[1]), min(m2[2], m2[3]));
    int rg2 = __shfl(g2, 63 - lane);
    int im2 = wave_iscan_min_i32(rg2);
    int tot2m = __builtin_amdgcn_readlane(im2, 63);   // min over all half-2
    int pm2 = __shfl_up(im2, 1);
    int er2 = (lane == 0) ? INFB : pm2;
    int sg2 = __shfl(er2, 63 - lane);                 // min over groups > lane
    int f2[4];
    f2[3] = sg2;
    f2[2] = min(m2[3], f2[3]);
    f2[1] = min(m2[2], f2[2]);
    f2[0] = min(m2[1], f2[1]);
    int m1[4] = {ma.x, ma.y, ma.z, ma.w};
    int g1 = min(min(m1[0], m1[1]), min(m1[2], m1[3]));
    int rg1 = __shfl(g1, 63 - lane);
    int im1 = wave_iscan_min_i32(rg1);
    int pm1 = __shfl_up(im1, 1);
    int er1 = (lane == 0) ? INFB : pm1;
    int sg1 = __shfl(er1, 63 - lane);
    int f1[4];
    f1[3] = min(sg1, tot2m);
    f1[2] = min(m1[3], f1[3]);
    f1[1] = min(m1[2], f1[2]);
    f1[0] = min(m1[1], f1[1]);
    reinterpret_cast<int4*>(sfx)[lane]      = make_int4(f1[0], f1[1], f1[2], f1[3]);
    reinterpret_cast<int4*>(sfx)[lane + 64] = make_int4(f2[0], f2[1], f2[2], f2[3]);
}

// Reorder-free solver over positions [cStart, cEnd) (cEnd multiple of CHUNK).
// Position-order block scans of (w, w*t); per-position time-order correction
// via mates loop; next-event time from later mates + bucket suffix-min + tEnd.
// mloc accumulates per-thread valid-candidate min (reduce after the call).
__device__ __forceinline__ void solve_range(
    const float* s_t, const float* s_w, const int* pck, const int* sfx,
    float* s_fw, float* s_fwt,
    int cStart, int cEnd, int posLo, int posValidEnd,
    float t0f, float bscale, int baseOff, float tEnd, float theta,
    int tid, int lane, int wid, float& cumW, float& cumWT, float& mloc)
{
    for (int c0 = cStart; c0 < cEnd; c0 += CHUNK) {
        const int p = c0 + tid;
        const bool valid = (p >= posLo);
        float t_p = s_t[p];
        float w_p = valid ? s_w[p] : 0.f;

        float xw  = wave_iscan_f32(w_p);
        float xwt = wave_iscan_f32(w_p * t_p);
        if (lane == 63) { s_fw[wid] = xw; s_fwt[wid] = xwt; }
        __syncthreads();                                   // partials visible
        float W = cumW, WT = cumWT;
        for (int k2 = 0; k2 < wid; ++k2) { W += s_fw[k2]; WT += s_fwt[k2]; }
        W += xw; WT += xwt;                                // inclusive @ p (position order)
        cumW  += s_fw[0] + s_fw[1] + s_fw[2] + s_fw[3];
        cumWT += s_fwt[0] + s_fwt[1] + s_fwt[2] + s_fwt[3];

        if (valid && p < posValidEnd) {
            int k = clampb((int)((t_p - t0f) * bscale));   // same expr as hist binning
            int pk = pck[k];
            int bas = (pk >> 12) + baseOff, cn = pk & 0xfff;
            float tnx = fminf(__int_as_float(sfx[k]), tEnd);
            if (cn > 1) {
                for (int q = bas; q < bas + cn; ++q) {
                    if (q == p) continue;
                    float tq = s_t[q], wq = s_w[q];
                    bool earlier = (tq < t_p) || (tq == t_p && q < p);
                    bool posb = (q < p);
                    // correct position-prefix to time-prefix
                    W  += (earlier ? wq      : 0.f) - (posb ? wq      : 0.f);
                    WT += (earlier ? wq * tq : 0.f) - (posb ? wq * tq : 0.f);
                    if (!earlier) tnx = fminf(tnx, tq);
                }
            }
            if (W > 0.f) {
                float tmp = (theta + WT) * __builtin_amdgcn_rcpf(W);
                if (tmp >= t_p && tmp <= tnx) mloc = fminf(mloc, tmp);
            }
        }
        if (c0 + CHUNK < cEnd) __syncthreads();            // protect s_fw reuse
    }
}

__device__ __forceinline__ float block_min(float v, float* s_red, int lane, int wid) {
    v = wave_min_f32(v);
    if (lane == 0) s_red[wid] = v;
    __syncthreads();
    return fminf(fminf(s_red[0], s_red[1]), fminf(s_red[2], s_red[3]));
}

__global__ __launch_bounds__(TPB, 8) void equaltime_kernel(
    const float* __restrict__ spikes,     // [B][PRE]
    const float* __restrict__ weights,    // [PRE][POST]
    const float* __restrict__ delays,     // [PRE][POST]
    const float* __restrict__ thresholds, // [POST]
    float* __restrict__ out)              // [B][POST]
{
    __shared__ __align__(16) float s_t[PRE];    // 4 KB
    __shared__ __align__(16) float s_w[PRE];    // 4 KB
    __shared__ __align__(16) int   s_raw[NB];   // 2 KB counts
    __shared__ __align__(16) int   s_pck[NB];   // 2 KB packed (off<<12|cnt)
    __shared__ __align__(16) int   s_minT[NB];  // 2 KB bucket min t (bits)
    __shared__ __align__(16) int   s_sfx[NB];   // 2 KB suffix-min over later buckets
    __shared__ float s_fw[4], s_fwt[4];
    __shared__ float s_red[4];
    __shared__ int   s_nlow;

    const int tid  = threadIdx.x;
    const int lane = tid & 63;
    const int wid  = tid >> 6;

    // XCD-contiguous swizzle for weight/delay L2 locality
    const int bx   = blockIdx.x;
    const int sbx  = (bx & 7) * 512 + (bx >> 3);
    const int post = sbx >> 2;            // 4 WGs per post
    const int b0   = (sbx & 3) * BPW;
    const float theta = thresholds[post];

    float dly[EPT], wgt[EPT];
#pragma unroll
    for (int j = 0; j < EPT; ++j) {
        int pre = tid * EPT + j;
        dly[j] = delays[pre * POST + post];
        wgt[j] = weights[pre * POST + post];
    }

    // init counts + minT once (re-inits are folded into each batch)
    if (tid < 128) {
        reinterpret_cast<int4*>(s_raw)[tid]  = make_int4(0, 0, 0, 0);
        reinterpret_cast<int4*>(s_minT)[tid] = make_int4(INFB, INFB, INFB, INFB);
    }
    __syncthreads();

    for (int bi = 0; bi < BPW; ++bi) {
        const int b = b0 + bi;

        // ---- times; hist (cnt + minT) of t<TCUT; min of the rest ----
        float4 sp = *reinterpret_cast<const float4*>(spikes + b * PRE + tid * EPT);
        float tv[EPT] = {sp.x + dly[0], sp.y + dly[1], sp.z + dly[2], sp.w + dly[3]};
        int bkt[EPT], rnk[EPT];
        float mloc = INFINITY;
#pragma unroll
        for (int j = 0; j < EPT; ++j) {
            int k = (int)(tv[j] * BSCALE);
            bkt[j] = k;
            if (k < NB) {
                rnk[j] = atomicAdd(&s_raw[k], 1);
                atomicMin(&s_minT[k], __float_as_int(tv[j]));
            } else {
                mloc = fminf(mloc, tv[j]);
            }
        }
        mloc = wave_min_f32(mloc);
        __syncthreads();                                   // B1: hist final

        if (lane == 0) s_red[wid] = mloc;                  // read post-B2
        if (wid == 0)
            scan_and_suffix(s_raw, s_pck, s_minT, s_sfx, &s_nlow, lane);
        __syncthreads();                                   // B2: pck/sfx/nlow/s_red

        const int N_low = s_nlow;
        const float minExcl = fminf(fminf(s_red[0], s_red[1]),
                                    fminf(s_red[2], s_red[3]));

        // ---- scatter (arrival order in bucket); pad holes; re-inits ----
#pragma unroll
        for (int j = 0; j < EPT; ++j) {
            if (bkt[j] < NB) {
                int pos = (s_pck[bkt[j]] >> 12) + rnk[j];
                s_t[pos] = tv[j];
                s_w[pos] = wgt[j];
            }
        }
        if (wid == 1) {   // s_raw reads done at B2; contiguous zero
            reinterpret_cast<int4*>(s_raw)[lane]      = make_int4(0, 0, 0, 0);
            reinterpret_cast<int4*>(s_raw)[lane + 64] = make_int4(0, 0, 0, 0);
        }
        if (wid == 2)
            reinterpret_cast<int4*>(s_minT)[lane]      = make_int4(INFB, INFB, INFB, INFB);
        if (wid == 3)
            reinterpret_cast<int4*>(s_minT)[lane + 64] = make_int4(INFB, INFB, INFB, INFB);
        const int roundup = (N_low + CHUNK - 1) & ~(CHUNK - 1);
        int h = N_low + tid;
        if (h < roundup) { s_t[h] = minExcl; s_w[h] = 0.f; }
        __syncthreads();                                   // B3: scatter+zero visible

        // ---- solve low region (no reorder, no early exit) ----
        float cumW = 0.f, cumWT = 0.f, mcand = INFINITY;
        solve_range(s_t, s_w, s_pck, s_sfx, s_fw, s_fwt,
                    0, roundup, 0, N_low, 0.f, BSCALE, 0, minExcl, theta,
                    tid, lane, wid, cumW, cumWT, mcand);
        float mAll = block_min(mcand, s_red, lane, wid);   // B4

        // ---- rare exact fallback: no valid crossing among t < TCUT ----
        if (!(mAll < INFINITY) && N_low < PRE) {
#pragma unroll
            for (int j = 0; j < EPT; ++j) {
                if (bkt[j] >= NB) {
                    int k2 = clampb((int)((tv[j] - TCUTF) * BSCALE2));
                    bkt[j] = NB + k2;          // remember tail bucket
                    rnk[j] = atomicAdd(&s_raw[k2], 1);
                    atomicMin(&s_minT[k2], __float_as_int(tv[j]));
                }
            }
            __syncthreads();                               // hist final
            if (wid == 0)
                scan_and_suffix(s_raw, s_pck, s_minT, s_sfx, &s_nlow, lane);
            __syncthreads();                               // pck/sfx visible
#pragma unroll
            for (int j = 0; j < EPT; ++j) {
                if (bkt[j] >= NB) {
                    int k2 = bkt[j] - NB;
                    int pos = N_low + (s_pck[k2] >> 12) + rnk[j];
                    s_t[pos] = tv[j];
                    s_w[pos] = wgt[j];
                }
            }
            if (wid == 1) {   // re-init for next batch
                reinterpret_cast<int4*>(s_raw)[lane]      = make_int4(0, 0, 0, 0);
                reinterpret_cast<int4*>(s_raw)[lane + 64] = make_int4(0, 0, 0, 0);
            }
            if (wid == 2)
                reinterpret_cast<int4*>(s_minT)[lane]      = make_int4(INFB, INFB, INFB, INFB);
            if (wid == 3)
                reinterpret_cast<int4*>(s_minT)[lane + 64] = make_int4(INFB, INFB, INFB, INFB);
            __syncthreads();                               // scatter+zero visible
            solve_range(s_t, s_w, s_pck, s_sfx, s_fw, s_fwt,
                        N_low & ~(CHUNK - 1), PRE, N_low, PRE,
                        TCUTF, BSCALE2, N_low, INFINITY, theta,
                        tid, lane, wid, cumW, cumWT, mcand);
            mAll = block_min(mcand, s_red, lane, wid);
        }

        if (tid == 0) out[b * POST + post] = mAll;
        // No trailing barrier: next batch's hist atomics target buffers whose
        // re-init was barrier-ordered (B3/B4) before any post-barrier reader.
    }
}

extern "C" void kernel_launch(void* const* d_in, const int* in_sizes, int n_in,
                              void* d_out, int out_size, void* d_ws, size_t ws_size,
                              hipStream_t stream) {
    const float* spikes     = (const float*)d_in[0]; // [32,1024]
    const float* weights    = (const float*)d_in[1]; // [1024,1024]
    const float* delays     = (const float*)d_in[2]; // [1024,1024]
    const float* thresholds = (const float*)d_in[3]; // [1024]
    float* outp = (float*)d_out;                     // [32,1024]

    dim3 grid(POST * (B_TOT / BPW)); // 4096 workgroups
    dim3 block(TPB);
    equaltime_kernel<<<grid, block, 0, stream>>>(spikes, weights, delays, thresholds, outp);
}

// Round 3
// 157.805 us; speedup vs baseline: 1.5477x; 1.0655x over previous
//
#include <hip/hip_runtime.h>
#include <math.h>

// EqualtimeLayer R16 = R15 structure with the spill fixed.
// R15 post-mortem: WRITE_SIZE 33.8MB (vs 128KB output) + VALUBusy 47% =>
// scratch spills. Cause: __launch_bounds__(256,8) caps VGPRs at 64/wave;
// R15's live set (dly/wgt/tv/bkt/rnk + solver temps) exceeds it. Measured
// occupancy was only ~70% anyway, so the 8-block cap bought nothing.
// Fixes:
//  - __launch_bounds__(256, 6): VGPR budget ~85, occupancy cap 75% (= today's
//    measured level).
//  - bkt[4] deleted; bucket index recomputed from tv[j] (same float expr =>
//    bit-identical bucket). Only rnk[4] (atomic results) persists.
// Solver itself unchanged from R15 (proven exact, absmax == R13 baseline):
// hist(cnt+minT) -> wave-0 scan+suffix-min -> scatter -> position-order block
// scans + per-thread mates correction; min over all valid candidates (validity
// monotone in k => no early exit needed). 5 barriers/batch. Rare tail stage.

#define B_TOT 32
#define PRE 1024
#define POST 1024
#define NB 512
#define TPB 256
#define EPT 4
#define BPW 8
#define CHUNK 256
#define TCUTF 0.625f
#define BSCALE 819.2f          // 512 buckets over [0, 0.625)
#define BSCALE2 372.36363636f  // 512 buckets over [0.625, 2.0)
#define INFB 0x7F800000

// ---- DPP helpers (gfx9 encodings) ----
template<int CTRL, int MASK>
__device__ __forceinline__ int dpp_add_i32(int v) {
    return v + __builtin_amdgcn_update_dpp(0, v, CTRL, MASK, 0xf, true);
}
template<int CTRL, int MASK>
__device__ __forceinline__ float dpp_add_f32(float v) {
    int t = __builtin_amdgcn_update_dpp(0, __float_as_int(v), CTRL, MASK, 0xf, true);
    return v + __int_as_float(t);
}
template<int CTRL, int MASK>
__device__ __forceinline__ int dpp_min_i32(int v) {
    // old = +INF bits, bound_ctrl=false: missing lanes contribute min identity
    int t = __builtin_amdgcn_update_dpp(INFB, v, CTRL, MASK, 0xf, false);
    return min(v, t);
}
template<int CTRL>
__device__ __forceinline__ float dpp_min_f32(float v) {
    int t = __builtin_amdgcn_update_dpp(__float_as_int(v), __float_as_int(v), CTRL, 0xf, 0xf, false);
    return fminf(v, __int_as_float(t));
}
__device__ __forceinline__ int wave_iscan_i32(int v) {
    v = dpp_add_i32<0x111, 0xf>(v);
    v = dpp_add_i32<0x112, 0xf>(v);
    v = dpp_add_i32<0x114, 0xf>(v);
    v = dpp_add_i32<0x118, 0xf>(v);
    v = dpp_add_i32<0x142, 0xa>(v);
    v = dpp_add_i32<0x143, 0xc>(v);
    return v;
}
__device__ __forceinline__ float wave_iscan_f32(float v) {
    v = dpp_add_f32<0x111, 0xf>(v);
    v = dpp_add_f32<0x112, 0xf>(v);
    v = dpp_add_f32<0x114, 0xf>(v);
    v = dpp_add_f32<0x118, 0xf>(v);
    v = dpp_add_f32<0x142, 0xa>(v);
    v = dpp_add_f32<0x143, 0xc>(v);
    return v;
}
__device__ __forceinline__ int wave_iscan_min_i32(int v) {
    v = dpp_min_i32<0x111, 0xf>(v);
    v = dpp_min_i32<0x112, 0xf>(v);
    v = dpp_min_i32<0x114, 0xf>(v);
    v = dpp_min_i32<0x118, 0xf>(v);
    v = dpp_min_i32<0x142, 0xa>(v);
    v = dpp_min_i32<0x143, 0xc>(v);
    return v;
}
__device__ __forceinline__ float wave_min_f32(float v) {
    v = fminf(v, __shfl_down(v, 32));
    v = fminf(v, __shfl_down(v, 16));
    v = dpp_min_f32<0x140>(v);
    v = dpp_min_f32<0x141>(v);
    v = dpp_min_f32<0x4E>(v);
    v = dpp_min_f32<0xB1>(v);
    return v;
}
__device__ __forceinline__ int clampb(int k) {
    return k < 0 ? 0 : (k > NB - 1 ? NB - 1 : k);
}

// Wave-0-only: exclusive scan of NB counts (raw -> pck, packed off<<12|cnt),
// suffix-min of bucket minT (mnt -> sfx: min t over buckets STRICTLY later),
// total count -> *nout. Layout: half1 = buckets[4L..4L+3] at int4 [lane],
// half2 = buckets[256+4L..] at [lane+64] (R13-proven conflict-free).
__device__ __forceinline__ void scan_and_suffix(const int* raw, int* pck,
                                                const int* mnt, int* sfx,
                                                int* nout, int lane) {
    int4 a = reinterpret_cast<const int4*>(raw)[lane];
    int4 b = reinterpret_cast<const int4*>(raw)[lane + 64];
    int c1[4] = {a.x, a.y, a.z, a.w};
    int c2[4] = {b.x, b.y, b.z, b.w};
    int ls1[4], ls2[4];
    int s1 = 0, s2 = 0;
#pragma unroll
    for (int j = 0; j < 4; ++j) { s1 += c1[j]; ls1[j] = s1; }
#pragma unroll
    for (int j = 0; j < 4; ++j) { s2 += c2[j]; ls2[j] = s2; }
    int x1 = wave_iscan_i32(s1);
    int x2 = wave_iscan_i32(s2);
    int tot1 = __builtin_amdgcn_readlane(x1, 63);
    int tot2 = __builtin_amdgcn_readlane(x2, 63);
    int e1 = x1 - s1;
    int e2 = tot1 + x2 - s2;
    {
        int o1[4], o2[4];
#pragma unroll
        for (int j = 0; j < 4; ++j) {
            o1[j] = ((e1 + ls1[j] - c1[j]) << 12) | c1[j];
            o2[j] = ((e2 + ls2[j] - c2[j]) << 12) | c2[j];
        }
        reinterpret_cast<int4*>(pck)[lane]      = make_int4(o1[0], o1[1], o1[2], o1[3]);
        reinterpret_cast<int4*>(pck)[lane + 64] = make_int4(o2[0], o2[1], o2[2], o2[3]);
    }
    if (lane == 0) *nout = tot1 + tot2;

    // ---- suffix-min (reversed iscan-min; R14-verified pattern) ----
    int4 ma = reinterpret_cast<const int4*>(mnt)[lane];
    int4 mb = reinterpret_cast<const int4*>(mnt)[lane + 64];
    // half 2 first (its total feeds half 1)
    int m2[4] = {mb.x, mb.y, mb.z, mb.w};
    int g2 = min(min(m2[0], m2[1]), min(m2[2], m2[3]));
    int rg2 = __shfl(g2, 63 - lane);
    int im2 = wave_iscan_min_i32(rg2);
    int tot2m = __builtin_amdgcn_readlane(im2, 63);   // min over all half-2
    int pm2 = __shfl_up(im2, 1);
    int er2 = (lane == 0) ? INFB : pm2;
    int sg2 = __shfl(er2, 63 - lane);                 // min over groups > lane
    int f2[4];
    f2[3] = sg2;
    f2[2] = min(m2[3], f2[3]);
    f2[1] = min(m2[2], f2[2]);
    f2[0] = min(m2[1], f2[1]);
    int m1[4] = {ma.x, ma.y, ma.z, ma.w};
    int g1 = min(min(m1[0], m1[1]), min(m1[2], m1[3]));
    int rg1 = __shfl(g1, 63 - lane);
    int im1 = wave_iscan_min_i32(rg1);
    int pm1 = __shfl_up(im1, 1);
    int er1 = (lane == 0) ? INFB : pm1;
    int sg1 = __shfl(er1, 63 - lane);
    int f1[4];
    f1[3] = min(sg1, tot2m);
    f1[2] = min(m1[3], f1[3]);
    f1[1] = min(m1[2], f1[2]);
    f1[0] = min(m1[1], f1[1]);
    reinterpret_cast<int4*>(sfx)[lane]      = make_int4(f1[0], f1[1], f1[2], f1[3]);
    reinterpret_cast<int4*>(sfx)[lane + 64] = make_int4(f2[0], f2[1], f2[2], f2[3]);
}

// Reorder-free solver over positions [cStart, cEnd) (cEnd multiple of CHUNK).
// Position-order block scans of (w, w*t); per-position time-order correction
// via mates loop; next-event time from later mates + bucket suffix-min + tEnd.
// mloc accumulates per-thread valid-candidate min (reduce after the call).
__device__ __forceinline__ void solve_range(
    const float* s_t, const float* s_w, const int* pck, const int* sfx,
    float* s_fw, float* s_fwt,
    int cStart, int cEnd, int posLo, int posValidEnd,
    float t0f, float bscale, int baseOff, float tEnd, float theta,
    int tid, int lane, int wid, float& cumW, float& cumWT, float& mloc)
{
    for (int c0 = cStart; c0 < cEnd; c0 += CHUNK) {
        const int p = c0 + tid;
        const bool valid = (p >= posLo);
        float t_p = s_t[p];
        float w_p = valid ? s_w[p] : 0.f;

        float xw  = wave_iscan_f32(w_p);
        float xwt = wave_iscan_f32(w_p * t_p);
        if (lane == 63) { s_fw[wid] = xw; s_fwt[wid] = xwt; }
        __syncthreads();                                   // partials visible
        float W = cumW, WT = cumWT;
        for (int k2 = 0; k2 < wid; ++k2) { W += s_fw[k2]; WT += s_fwt[k2]; }
        W += xw; WT += xwt;                                // inclusive @ p (position order)
        cumW  += s_fw[0] + s_fw[1] + s_fw[2] + s_fw[3];
        cumWT += s_fwt[0] + s_fwt[1] + s_fwt[2] + s_fwt[3];

        if (valid && p < posValidEnd) {
            int k = clampb((int)((t_p - t0f) * bscale));   // same expr as hist binning
            int pk = pck[k];
            int bas = (pk >> 12) + baseOff, cn = pk & 0xfff;
            float tnx = fminf(__int_as_float(sfx[k]), tEnd);
            if (cn > 1) {
                for (int q = bas; q < bas + cn; ++q) {
                    if (q == p) continue;
                    float tq = s_t[q], wq = s_w[q];
                    bool earlier = (tq < t_p) || (tq == t_p && q < p);
                    bool posb = (q < p);
                    // correct position-prefix to time-prefix
                    W  += (earlier ? wq      : 0.f) - (posb ? wq      : 0.f);
                    WT += (earlier ? wq * tq : 0.f) - (posb ? wq * tq : 0.f);
                    if (!earlier) tnx = fminf(tnx, tq);
                }
            }
            if (W > 0.f) {
                float tmp = (theta + WT) * __builtin_amdgcn_rcpf(W);
                if (tmp >= t_p && tmp <= tnx) mloc = fminf(mloc, tmp);
            }
        }
        if (c0 + CHUNK < cEnd) __syncthreads();            // protect s_fw reuse
    }
}

__device__ __forceinline__ float block_min(float v, float* s_red, int lane, int wid) {
    v = wave_min_f32(v);
    if (lane == 0) s_red[wid] = v;
    __syncthreads();
    return fminf(fminf(s_red[0], s_red[1]), fminf(s_red[2], s_red[3]));
}

__global__ __launch_bounds__(TPB, 6) void equaltime_kernel(
    const float* __restrict__ spikes,     // [B][PRE]
    const float* __restrict__ weights,    // [PRE][POST]
    const float* __restrict__ delays,     // [PRE][POST]
    const float* __restrict__ thresholds, // [POST]
    float* __restrict__ out)              // [B][POST]
{
    __shared__ __align__(16) float s_t[PRE];    // 4 KB
    __shared__ __align__(16) float s_w[PRE];    // 4 KB
    __shared__ __align__(16) int   s_raw[NB];   // 2 KB counts
    __shared__ __align__(16) int   s_pck[NB];   // 2 KB packed (off<<12|cnt)
    __shared__ __align__(16) int   s_minT[NB];  // 2 KB bucket min t (bits)
    __shared__ __align__(16) int   s_sfx[NB];   // 2 KB suffix-min over later buckets
    __shared__ float s_fw[4], s_fwt[4];
    __shared__ float s_red[4];
    __shared__ int   s_nlow;

    const int tid  = threadIdx.x;
    const int lane = tid & 63;
    const int wid  = tid >> 6;

    // XCD-contiguous swizzle for weight/delay L2 locality
    const int bx   = blockIdx.x;
    const int sbx  = (bx & 7) * 512 + (bx >> 3);
    const int post = sbx >> 2;            // 4 WGs per post
    const int b0   = (sbx & 3) * BPW;
    const float theta = thresholds[post];

    float dly[EPT], wgt[EPT];
#pragma unroll
    for (int j = 0; j < EPT; ++j) {
        int pre = tid * EPT + j;
        dly[j] = delays[pre * POST + post];
        wgt[j] = weights[pre * POST + post];
    }

    // init counts + minT once (re-inits are folded into each batch)
    if (tid < 128) {
        reinterpret_cast<int4*>(s_raw)[tid]  = make_int4(0, 0, 0, 0);
        reinterpret_cast<int4*>(s_minT)[tid] = make_int4(INFB, INFB, INFB, INFB);
    }
    __syncthreads();

    for (int bi = 0; bi < BPW; ++bi) {
        const int b = b0 + bi;

        // ---- times; hist (cnt + minT) of t<TCUT; min of the rest ----
        float4 sp = *reinterpret_cast<const float4*>(spikes + b * PRE + tid * EPT);
        float tv[EPT] = {sp.x + dly[0], sp.y + dly[1], sp.z + dly[2], sp.w + dly[3]};
        int rnk[EPT];
        float mloc = INFINITY;
#pragma unroll
        for (int j = 0; j < EPT; ++j) {
            int k = (int)(tv[j] * BSCALE);      // bucket recomputed on use; no bkt[] array
            if (k < NB) {
                rnk[j] = atomicAdd(&s_raw[k], 1);
                atomicMin(&s_minT[k], __float_as_int(tv[j]));
            } else {
                mloc = fminf(mloc, tv[j]);
            }
        }
        mloc = wave_min_f32(mloc);
        __syncthreads();                                   // B1: hist final

        if (lane == 0) s_red[wid] = mloc;                  // read post-B2
        if (wid == 0)
            scan_and_suffix(s_raw, s_pck, s_minT, s_sfx, &s_nlow, lane);
        __syncthreads();                                   // B2: pck/sfx/nlow/s_red

        const int N_low = s_nlow;
        const float minExcl = fminf(fminf(s_red[0], s_red[1]),
                                    fminf(s_red[2], s_red[3]));

        // ---- scatter (arrival order in bucket); pad holes; re-inits ----
#pragma unroll
        for (int j = 0; j < EPT; ++j) {
            int k = (int)(tv[j] * BSCALE);
            if (k < NB) {
                int pos = (s_pck[k] >> 12) + rnk[j];
                s_t[pos] = tv[j];
                s_w[pos] = wgt[j];
            }
        }
        if (wid == 1) {   // s_raw reads done at B2; contiguous zero
            reinterpret_cast<int4*>(s_raw)[lane]      = make_int4(0, 0, 0, 0);
            reinterpret_cast<int4*>(s_raw)[lane + 64] = make_int4(0, 0, 0, 0);
        }
        if (wid == 2)
            reinterpret_cast<int4*>(s_minT)[lane]      = make_int4(INFB, INFB, INFB, INFB);
        if (wid == 3)
            reinterpret_cast<int4*>(s_minT)[lane + 64] = make_int4(INFB, INFB, INFB, INFB);
        const int roundup = (N_low + CHUNK - 1) & ~(CHUNK - 1);
        int h = N_low + tid;
        if (h < roundup) { s_t[h] = minExcl; s_w[h] = 0.f; }
        __syncthreads();                                   // B3: scatter+zero visible

        // ---- solve low region (no reorder, no early exit) ----
        float cumW = 0.f, cumWT = 0.f, mcand = INFINITY;
        solve_range(s_t, s_w, s_pck, s_sfx, s_fw, s_fwt,
                    0, roundup, 0, N_low, 0.f, BSCALE, 0, minExcl, theta,
                    tid, lane, wid, cumW, cumWT, mcand);
        float mAll = block_min(mcand, s_red, lane, wid);   // B4

        // ---- rare exact fallback: no valid crossing among t < TCUT ----
        if (!(mAll < INFINITY) && N_low < PRE) {
#pragma unroll
            for (int j = 0; j < EPT; ++j) {
                if ((int)(tv[j] * BSCALE) >= NB) {         // tail event
                    int k2 = clampb((int)((tv[j] - TCUTF) * BSCALE2));
                    rnk[j] = atomicAdd(&s_raw[k2], 1);
                    atomicMin(&s_minT[k2], __float_as_int(tv[j]));
                }
            }
            __syncthreads();                               // hist final
            if (wid == 0)
                scan_and_suffix(s_raw, s_pck, s_minT, s_sfx, &s_nlow, lane);
            __syncthreads();                               // pck/sfx visible
#pragma unroll
            for (int j = 0; j < EPT; ++j) {
                if ((int)(tv[j] * BSCALE) >= NB) {
                    int k2 = clampb((int)((tv[j] - TCUTF) * BSCALE2));
                    int pos = N_low + (s_pck[k2] >> 12) + rnk[j];
                    s_t[pos] = tv[j];
                    s_w[pos] = wgt[j];
                }
            }
            if (wid == 1) {   // re-init for next batch
                reinterpret_cast<int4*>(s_raw)[lane]      = make_int4(0, 0, 0, 0);
                reinterpret_cast<int4*>(s_raw)[lane + 64] = make_int4(0, 0, 0, 0);
            }
            if (wid == 2)
                reinterpret_cast<int4*>(s_minT)[lane]      = make_int4(INFB, INFB, INFB, INFB);
            if (wid == 3)
                reinterpret_cast<int4*>(s_minT)[lane + 64] = make_int4(INFB, INFB, INFB, INFB);
            __syncthreads();                               // scatter+zero visible
            solve_range(s_t, s_w, s_pck, s_sfx, s_fw, s_fwt,
                        N_low & ~(CHUNK - 1), PRE, N_low, PRE,
                        TCUTF, BSCALE2, N_low, INFINITY, theta,
                        tid, lane, wid, cumW, cumWT, mcand);
            mAll = block_min(mcand, s_red, lane, wid);
        }

        if (tid == 0) out[b * POST + post] = mAll;
        // No trailing barrier: next batch's hist atomics target buffers whose
        // re-init was barrier-ordered (B3/B4) before any post-barrier reader.
    }
}

extern "C" void kernel_launch(void* const* d_in, const int* in_sizes, int n_in,
                              void* d_out, int out_size, void* d_ws, size_t ws_size,
                              hipStream_t stream) {
    const float* spikes     = (const float*)d_in[0]; // [32,1024]
    const float* weights    = (const float*)d_in[1]; // [1024,1024]
    const float* delays     = (const float*)d_in[2]; // [1024,1024]
    const float* thresholds = (const float*)d_in[3]; // [1024]
    float* outp = (float*)d_out;                     // [32,1024]

    dim3 grid(POST * (B_TOT / BPW)); // 4096 workgroups
    dim3 block(TPB);
    equaltime_kernel<<<grid, block, 0, stream>>>(spikes, weights, delays, thresholds, outp);
}